// Round 4
// baseline (108.266 us; speedup 1.0000x reference)
//
#include <hip/hip_runtime.h>

#define NN 4194304
#define NB 16384

typedef _Float16 half8 __attribute__((ext_vector_type(8)));
typedef float floatx4 __attribute__((ext_vector_type(4)));
typedef unsigned int uint;

__device__ __forceinline__ uint pk_u32(float lo, float hi) {
  return __builtin_bit_cast(uint, __builtin_amdgcn_cvt_pkrtz(lo, hi));
}

// Segmented wave-level reduction + one atomic pair per run (batch sorted).
__device__ __forceinline__ void seg_atomic_add2(int b, float vx, float vy,
                                                float* __restrict__ out) {
  const int lane = threadIdx.x & 63;
  int bprev = __shfl_up(b, 1);
  bool head = (lane == 0) || (b != bprev);
  unsigned long long hb = __ballot(head);
  unsigned long long mask_le = hb << (63 - lane);
  int run_start = lane - __clzll(mask_le);
  float sx = vx, sy = vy;
#pragma unroll
  for (int off = 1; off < 64; off <<= 1) {
    float ox = __shfl_up(sx, off);
    float oy = __shfl_up(sy, off);
    if (lane - off >= run_start) { sx += ox; sy += oy; }
  }
  int bnext = __shfl_down(b, 1);
  bool tail = (lane == 63) || (b != bnext);
  if (tail) {
    atomicAdd(&out[2 * b], sx);
    atomicAdd(&out[2 * b + 1], sy);
  }
}

__global__ __launch_bounds__(256) void centroid_kernel(
    const float2* __restrict__ pos, const int* __restrict__ batch,
    float* __restrict__ csum) {
  int i = blockIdx.x * 256 + threadIdx.x;
  float2 p = pos[i];
  int b = batch[i];
  seg_atomic_add2(b, p.x, p.y, csum);
}

__global__ __launch_bounds__(256) void graphvec_kernel(
    const float* __restrict__ csum, const float2* __restrict__ poi_pos,
    float* __restrict__ udc) {
  int i = blockIdx.x * 256 + threadIdx.x;
  float2 pp = poi_pos[i];
  float dcx = csum[2 * i] - pp.x;
  float dcy = csum[2 * i + 1] - pp.y;
  float inv = rsqrtf(dcx * dcx + dcy * dcy);
  udc[2 * i] = dcx * inv;
  udc[2 * i + 1] = dcy * inv;
}

// Prepack weights into MFMA B-fragment order, 6 N-tiles of 16 cols x 32 k:
// tile0: L1 (10 out, K=3)   tile1: L2 cols 0-15 (K=10)  tile2: L2 cols 16-19
// tile3: L3 (10 out, K=20)  tile4: L4 (5 out, K=10)     tile5: L5 (1 out, K=5)
// Wf u32 layout: [tile][n(16)][u(16)] where u covers k=2u,2u+1 as packed f16.
// Bias Bf: [tile][n(16)] f32, zero padded.
__global__ void prepack_kernel(
    const float* __restrict__ W1, const float* __restrict__ W2,
    const float* __restrict__ W3, const float* __restrict__ W4,
    const float* __restrict__ W5, const float* __restrict__ B1,
    const float* __restrict__ B2, const float* __restrict__ B3,
    const float* __restrict__ B4, const float* __restrict__ B5,
    uint* __restrict__ Wf, float* __restrict__ Bf) {
  int p = blockIdx.x * 256 + threadIdx.x;
  if (p < 1536) {
    int tile = p >> 8, rem = p & 255, n = rem >> 4, u = rem & 15;
    int k0 = u * 2;
    const float* W;
    int outb = 0, outc, K, ld;
    switch (tile) {
      case 0: W = W1; outc = 10; K = 3;  ld = 3;  break;
      case 1: W = W2; outc = 16; K = 10; ld = 10; break;
      case 2: W = W2; outb = 16; outc = 4; K = 10; ld = 10; break;
      case 3: W = W3; outc = 10; K = 20; ld = 20; break;
      case 4: W = W4; outc = 5;  K = 10; ld = 10; break;
      default: W = W5; outc = 1; K = 5;  ld = 5;  break;
    }
    float a = (n < outc && k0 < K) ? W[(outb + n) * ld + k0] : 0.f;
    float b = (n < outc && k0 + 1 < K) ? W[(outb + n) * ld + k0 + 1] : 0.f;
    Wf[p] = pk_u32(a, b);
  } else if (p < 1536 + 96) {
    int q = p - 1536, tile = q >> 4, n = q & 15;
    float v = 0.f;
    switch (tile) {
      case 0: if (n < 10) v = B1[n]; break;
      case 1: v = B2[n]; break;
      case 2: if (n < 4) v = B2[16 + n]; break;
      case 3: if (n < 10) v = B3[n]; break;
      case 4: if (n < 5) v = B4[n]; break;
      default: if (n < 1) v = B5[0]; break;
    }
    Bf[q] = v;
  }
}

// D-fragment (4 f32, col=lane&15, rows nb..nb+3) -> LDS [node][32 f16] with ReLU.
__device__ __forceinline__ void store_relu(unsigned short* __restrict__ buf,
                                           int nb, int col, int cbase,
                                           floatx4 d) {
  float x0 = fmaxf(d[0], 0.f), x1 = fmaxf(d[1], 0.f);
  float x2 = fmaxf(d[2], 0.f), x3 = fmaxf(d[3], 0.f);
  uint p01 = pk_u32(x0, x1);
  uint p23 = pk_u32(x2, x3);
  int base = nb * 32 + cbase + col;
  buf[base] = (unsigned short)p01;
  buf[base + 32] = (unsigned short)(p01 >> 16);
  buf[base + 64] = (unsigned short)p23;
  buf[base + 96] = (unsigned short)(p23 >> 16);
}

__global__ __launch_bounds__(256) void main_kernel(
    const float* __restrict__ t, const float2* __restrict__ pos,
    const float* __restrict__ poi_t, const float2* __restrict__ poi_pos,
    const int* __restrict__ batch, const float2* __restrict__ udc,
    const uint* __restrict__ Wf, const float* __restrict__ Bf,
    float* __restrict__ out) {
  // Per-wave private LDS (no cross-wave sharing -> no barriers):
  // feat 544 u16 | bufA 512 u16 | bufB 512 u16 | wbuf 64 f32 (=128 u16)
  __shared__ unsigned short sh[4][1696];
  const int tid = threadIdx.x;
  const int lane = tid & 63;
  const int wid = tid >> 6;
  unsigned short* feat16 = sh[wid];
  unsigned short* bufA = sh[wid] + 544;
  unsigned short* bufB = sh[wid] + 1056;
  float* wbuf = (float*)(sh[wid] + 1568);

  // Zero this wave's LDS once (NaN-proof all garbage-K reads).
  {
    uint4* z = (uint4*)sh[wid];
    uint4 zero{0u, 0u, 0u, 0u};
    for (int i2 = lane; i2 < 212; i2 += 64) z[i2] = zero;
  }

  const int col = lane & 15;
  const int koct = lane >> 4;
  const int nb = koct * 4;

  // Wave-shared B fragments (per-lane slice) + bias splats.
  const int q = (col * 4 + koct) * 4;
  half8 bw[6];
  floatx4 cb[6];
#pragma unroll
  for (int tI = 0; tI < 6; ++tI) {
    uint4 raw = *(const uint4*)&Wf[tI * 256 + q];
    bw[tI] = __builtin_bit_cast(half8, raw);
    float bv = Bf[tI * 16 + col];
    floatx4 c;
    c[0] = bv; c[1] = bv; c[2] = bv; c[3] = bv;
    cb[tI] = c;
  }

  // Features (lane = node)
  int i = blockIdx.x * 256 + tid;
  int b = batch[i];
  float2 p = pos[i];
  float tv = t[i];
  float2 pp = poi_pos[b];
  float2 u = udc[b];
  float f0 = tv - poi_t[b];
  float dpx = p.x - pp.x, dpy = p.y - pp.y;
  float f1 = dpx * dpx + dpy * dpy;
  float inv_r = rsqrtf(f1);
  float f2 = (dpx * u.x + dpy * u.y) * inv_r;

  // feat[node][8 f16] = {f0,f1,f2,0,0,0,0,0}
  {
    uint4 fv{pk_u32(f0, f1), pk_u32(f2, 0.f), 0u, 0u};
    ((uint4*)feat16)[lane] = fv;
  }

  // 4 groups of 16 nodes; full MLP via 6 MFMAs per group.
#pragma unroll
  for (int g = 0; g < 4; ++g) {
    // L1: A from feat (rows 16B apart; k-octets >0 read finite junk x B=0)
    uint4 ar = ((const uint4*)feat16)[g * 16 + col + koct];
    half8 a = __builtin_bit_cast(half8, ar);
    floatx4 d = __builtin_amdgcn_mfma_f32_16x16x32_f16(a, bw[0], cb[0], 0, 0, 0);
    store_relu(bufA, nb, col, 0, d);

    // L2: 10 -> 20 (two N-tiles)
    ar = ((const uint4*)bufA)[col * 4 + koct];
    a = __builtin_bit_cast(half8, ar);
    floatx4 d2a = __builtin_amdgcn_mfma_f32_16x16x32_f16(a, bw[1], cb[1], 0, 0, 0);
    floatx4 d2b = __builtin_amdgcn_mfma_f32_16x16x32_f16(a, bw[2], cb[2], 0, 0, 0);
    store_relu(bufB, nb, col, 0, d2a);
    store_relu(bufB, nb, col, 16, d2b);

    // L3: 20 -> 10
    ar = ((const uint4*)bufB)[col * 4 + koct];
    a = __builtin_bit_cast(half8, ar);
    d = __builtin_amdgcn_mfma_f32_16x16x32_f16(a, bw[3], cb[3], 0, 0, 0);
    store_relu(bufA, nb, col, 0, d);

    // L4: 10 -> 5
    ar = ((const uint4*)bufA)[col * 4 + koct];
    a = __builtin_bit_cast(half8, ar);
    d = __builtin_amdgcn_mfma_f32_16x16x32_f16(a, bw[4], cb[4], 0, 0, 0);
    store_relu(bufB, nb, col, 0, d);

    // L5: 5 -> 1 (no ReLU); col 0 holds w for nodes g*16+nb..+3
    ar = ((const uint4*)bufB)[col * 4 + koct];
    a = __builtin_bit_cast(half8, ar);
    d = __builtin_amdgcn_mfma_f32_16x16x32_f16(a, bw[5], cb[5], 0, 0, 0);
    if (col == 0) ((uint4*)wbuf)[g * 4 + koct] = __builtin_bit_cast(uint4, d);
  }

  // Epilogue: per-lane weight, unit vector, segmented atomic reduce.
  float w = wbuf[lane];
  float nrm = fmaxf(sqrtf(f1), 1e-12f);
  float invn = 1.0f / nrm;
  seg_atomic_add2(b, w * dpx * invn, w * dpy * invn, out);
}

extern "C" void kernel_launch(void* const* d_in, const int* in_sizes, int n_in,
                              void* d_out, int out_size, void* d_ws,
                              size_t ws_size, hipStream_t stream) {
  const float* t = (const float*)d_in[0];
  const float2* pos = (const float2*)d_in[1];
  const float* poi_t = (const float*)d_in[2];
  const float2* poi_pos = (const float2*)d_in[3];
  const int* batch = (const int*)d_in[4];
  const float* W1 = (const float*)d_in[5];
  const float* B1 = (const float*)d_in[6];
  const float* W2 = (const float*)d_in[7];
  const float* B2 = (const float*)d_in[8];
  const float* W3 = (const float*)d_in[9];
  const float* B3 = (const float*)d_in[10];
  const float* W4 = (const float*)d_in[11];
  const float* B4 = (const float*)d_in[12];
  const float* W5 = (const float*)d_in[13];
  const float* B5 = (const float*)d_in[14];
  float* out = (float*)d_out;

  float* csum = (float*)d_ws;                  // [NB*2]
  float* udc = csum + 2 * NB;                  // [NB*2]
  uint* Wf = (uint*)(udc + 2 * NB);            // [1536]
  float* Bf = (float*)(Wf + 1536);             // [96]

  hipMemsetAsync(csum, 0, 2 * NB * sizeof(float), stream);
  hipMemsetAsync(d_out, 0, 2 * NB * sizeof(float), stream);

  prepack_kernel<<<7, 256, 0, stream>>>(W1, W2, W3, W4, W5, B1, B2, B3, B4,
                                        B5, Wf, Bf);
  centroid_kernel<<<NN / 256, 256, 0, stream>>>(pos, batch, csum);
  graphvec_kernel<<<NB / 256, 256, 0, stream>>>(csum, poi_pos, udc);
  main_kernel<<<NN / 256, 256, 0, stream>>>(
      t, pos, poi_t, poi_pos, batch, (const float2*)udc, Wf, Bf, out);
}

// Round 5
// 74.322 us; speedup vs baseline: 1.4567x; 1.4567x over previous
//
#include <hip/hip_runtime.h>

#define NN 4194304
#define NB 16384

typedef _Float16 half4 __attribute__((ext_vector_type(4)));
typedef float floatx4 __attribute__((ext_vector_type(4)));
typedef unsigned int uint;

__device__ __forceinline__ uint pk_u32(float lo, float hi) {
  return __builtin_bit_cast(uint, __builtin_amdgcn_cvt_pkrtz(lo, hi));
}

// D-fragment (4 f32) -> B-fragment (4 f16) with ReLU, all in-register.
// Valid because D: col=lane&15,row=(lane>>4)*4+r  ==  B: col=lane&15,k=(lane>>4)*4+i.
__device__ __forceinline__ half4 relu_cvt(floatx4 d) {
  uint2 u;
  u.x = pk_u32(d[0], d[1]);
  u.y = pk_u32(d[2], d[3]);
  half4 h = __builtin_bit_cast(half4, u);
  return __builtin_elementwise_max(h, half4{0, 0, 0, 0});
}

__device__ __forceinline__ half4 cvt_nr(floatx4 d) {  // no ReLU (last layer in)
  uint2 u;
  u.x = pk_u32(d[0], d[1]);
  u.y = pk_u32(d[2], d[3]);
  return __builtin_bit_cast(half4, u);
}

// Segmented wave-level reduction + one atomic pair per run (batch sorted).
__device__ __forceinline__ void seg_atomic_add2(int b, float vx, float vy,
                                                float* __restrict__ out) {
  const int lane = threadIdx.x & 63;
  int bprev = __shfl_up(b, 1);
  bool head = (lane == 0) || (b != bprev);
  unsigned long long hb = __ballot(head);
  unsigned long long mask_le = hb << (63 - lane);
  int run_start = lane - __clzll(mask_le);
  float sx = vx, sy = vy;
#pragma unroll
  for (int off = 1; off < 64; off <<= 1) {
    float ox = __shfl_up(sx, off);
    float oy = __shfl_up(sy, off);
    if (lane - off >= run_start) { sx += ox; sy += oy; }
  }
  int bnext = __shfl_down(b, 1);
  bool tail = (lane == 63) || (b != bnext);
  if (tail) {
    atomicAdd(&out[2 * b], sx);
    atomicAdd(&out[2 * b + 1], sy);
  }
}

__global__ __launch_bounds__(256) void centroid_kernel(
    const float2* __restrict__ pos, const int* __restrict__ batch,
    float* __restrict__ csum) {
  int i = blockIdx.x * 256 + threadIdx.x;
  float2 p = pos[i];
  int b = batch[i];
  seg_atomic_add2(b, p.x, p.y, csum);
}

__global__ __launch_bounds__(256) void graphvec_kernel(
    const float* __restrict__ csum, const float2* __restrict__ poi_pos,
    float* __restrict__ udc) {
  int i = blockIdx.x * 256 + threadIdx.x;
  float2 pp = poi_pos[i];
  float dcx = csum[2 * i] - pp.x;
  float dcy = csum[2 * i + 1] - pp.y;
  float inv = rsqrtf(dcx * dcx + dcy * dcy);
  udc[2 * i] = dcx * inv;
  udc[2 * i + 1] = dcy * inv;
}

// Prepack weights into A-fragments of mfma_f32_16x16x16f16 (W as A: M=out,K=in):
// A[row=lane&15][k=(lane>>4)*4 + i], i=0..3, stored as uint2 (4 packed f16).
// 7 tiles: 0:L1(10x3) 1:L2 rows0-15(16x10) 2:L2 rows16-19(4x10)
//          3:L3 k0-15(10x16of20) 4:L3 k16-19(10x4) 5:L4(5x10) 6:L5(1x5)
// Bias sets (6 x 16 f32): 0:B1 1:B2[0:16] 2:B2[16:20] 3:B3 4:B4 5:B5
__global__ void prepack_kernel(
    const float* __restrict__ W1, const float* __restrict__ W2,
    const float* __restrict__ W3, const float* __restrict__ W4,
    const float* __restrict__ W5, const float* __restrict__ B1,
    const float* __restrict__ B2, const float* __restrict__ B3,
    const float* __restrict__ B4, const float* __restrict__ B5,
    uint2* __restrict__ Wf, float* __restrict__ Bf) {
  int p = blockIdx.x * 256 + threadIdx.x;
  if (p < 448) {
    int tile = p >> 6, lane = p & 63, row = lane & 15, kb = (lane >> 4) * 4;
    const float* W;
    int outb = 0, outc, K, ld, koff = 0;
    switch (tile) {
      case 0: W = W1; outc = 10; K = 3;  ld = 3;  break;
      case 1: W = W2; outc = 16; K = 10; ld = 10; break;
      case 2: W = W2; outb = 16; outc = 4; K = 10; ld = 10; break;
      case 3: W = W3; outc = 10; K = 16; ld = 20; break;
      case 4: W = W3; outc = 10; K = 4;  ld = 20; koff = 16; break;
      case 5: W = W4; outc = 5;  K = 10; ld = 10; break;
      default: W = W5; outc = 1; K = 5;  ld = 5;  break;
    }
    float v[4];
#pragma unroll
    for (int i = 0; i < 4; ++i) {
      int k = kb + i;
      v[i] = (row < outc && k < K) ? W[(outb + row) * ld + koff + k] : 0.f;
    }
    Wf[p] = uint2{pk_u32(v[0], v[1]), pk_u32(v[2], v[3])};
  } else if (p < 448 + 96) {
    int q = p - 448, set = q >> 4, n = q & 15;
    float v = 0.f;
    switch (set) {
      case 0: if (n < 10) v = B1[n]; break;
      case 1: v = B2[n]; break;
      case 2: if (n < 4) v = B2[16 + n]; break;
      case 3: if (n < 10) v = B3[n]; break;
      case 4: if (n < 5) v = B4[n]; break;
      default: if (n < 1) v = B5[0]; break;
    }
    Bf[q] = v;
  }
}

__device__ __forceinline__ floatx4 mfma16(half4 a, half4 b, floatx4 c) {
  return __builtin_amdgcn_mfma_f32_16x16x16f16(a, b, c, 0, 0, 0);
}

__global__ __launch_bounds__(256) void main_kernel(
    const float* __restrict__ t, const float2* __restrict__ pos,
    const float* __restrict__ poi_t, const float2* __restrict__ poi_pos,
    const int* __restrict__ batch, const float2* __restrict__ udc,
    const uint2* __restrict__ Wf, const float* __restrict__ Bf,
    float* __restrict__ out) {
  // Wave-private LDS, no barriers (intra-wave producer/consumer only).
  __shared__ uint2 feat_s[4][64];   // 4 f16 feats per node
  __shared__ float wbuf_s[4][64];   // final MLP scalar per node
  const int tid = threadIdx.x;
  const int lane = tid & 63;
  const int wid = tid >> 6;
  uint2* feat = feat_s[wid];
  float* wbuf = wbuf_s[wid];
  const int col = lane & 15;
  const int koct = lane >> 4;

  // Weight A-fragments (7 tiles x 4 f16) + bias C-fragments (6 x 4 f32).
  half4 wa[7];
#pragma unroll
  for (int k = 0; k < 7; ++k)
    wa[k] = __builtin_bit_cast(half4, Wf[k * 64 + lane]);
  floatx4 cb[6];
#pragma unroll
  for (int s = 0; s < 6; ++s)
    cb[s] = *(const floatx4*)&Bf[s * 16 + koct * 4];

  // Per-node features (thread = node).
  int i = blockIdx.x * 256 + tid;
  int b = batch[i];
  float2 p = pos[i];
  float tv = t[i];
  float2 pp = poi_pos[b];
  float2 u = udc[b];
  float f0 = tv - poi_t[b];
  float dpx = p.x - pp.x, dpy = p.y - pp.y;
  float f1 = dpx * dpx + dpy * dpy;
  float inv_r = rsqrtf(f1);
  float f2 = (dpx * u.x + dpy * u.y) * inv_r;

  feat[lane] = uint2{pk_u32(f0, f1), pk_u32(f2, 0.f)};

  // 4 groups of 16 nodes; 7 MFMAs per group, transitions fully in-register.
#pragma unroll
  for (int g = 0; g < 4; ++g) {
    // B1: col=node, k=feat; only koct 0 holds real k (0..3), rest zero.
    uint2 fr = feat[g * 16 + col];
    if (koct != 0) { fr.x = 0u; fr.y = 0u; }
    half4 b1 = __builtin_bit_cast(half4, fr);

    floatx4 d1 = mfma16(wa[0], b1, cb[0]);               // L1: 3->10
    half4 a2 = relu_cvt(d1);
    floatx4 d2a = mfma16(wa[1], a2, cb[1]);              // L2: 10->20 (two M tiles)
    floatx4 d2b = mfma16(wa[2], a2, cb[2]);
    half4 a3a = relu_cvt(d2a);
    half4 a3b = relu_cvt(d2b);
    floatx4 d3 = mfma16(wa[3], a3a, cb[3]);              // L3: 20->10 (K chained)
    d3 = mfma16(wa[4], a3b, d3);
    half4 a4 = relu_cvt(d3);
    floatx4 d4 = mfma16(wa[5], a4, cb[4]);               // L4: 10->5
    half4 a5 = relu_cvt(d4);
    floatx4 d5 = mfma16(wa[6], a5, cb[5]);               // L5: 5->1 (no relu)

    // w for node g*16+col sits at row 0 -> koct==0, reg 0.
    if (lane < 16) wbuf[g * 16 + lane] = d5[0];
  }

  float w = wbuf[lane];
  float nrm = fmaxf(sqrtf(f1), 1e-12f);
  float invn = 1.0f / nrm;
  seg_atomic_add2(b, w * dpx * invn, w * dpy * invn, out);
}

extern "C" void kernel_launch(void* const* d_in, const int* in_sizes, int n_in,
                              void* d_out, int out_size, void* d_ws,
                              size_t ws_size, hipStream_t stream) {
  const float* t = (const float*)d_in[0];
  const float2* pos = (const float2*)d_in[1];
  const float* poi_t = (const float*)d_in[2];
  const float2* poi_pos = (const float2*)d_in[3];
  const int* batch = (const int*)d_in[4];
  const float* W1 = (const float*)d_in[5];
  const float* B1 = (const float*)d_in[6];
  const float* W2 = (const float*)d_in[7];
  const float* B2 = (const float*)d_in[8];
  const float* W3 = (const float*)d_in[9];
  const float* B3 = (const float*)d_in[10];
  const float* W4 = (const float*)d_in[11];
  const float* B4 = (const float*)d_in[12];
  const float* W5 = (const float*)d_in[13];
  const float* B5 = (const float*)d_in[14];
  float* out = (float*)d_out;

  float* csum = (float*)d_ws;                  // [NB*2]
  float* udc = csum + 2 * NB;                  // [NB*2]
  uint2* Wf = (uint2*)(udc + 2 * NB);          // [448]
  float* Bf = (float*)(Wf + 448);              // [96]

  hipMemsetAsync(csum, 0, 2 * NB * sizeof(float), stream);
  hipMemsetAsync(d_out, 0, 2 * NB * sizeof(float), stream);

  prepack_kernel<<<3, 256, 0, stream>>>(W1, W2, W3, W4, W5, B1, B2, B3, B4,
                                        B5, Wf, Bf);
  centroid_kernel<<<NN / 256, 256, 0, stream>>>(pos, batch, csum);
  graphvec_kernel<<<NB / 256, 256, 0, stream>>>(csum, poi_pos, udc);
  main_kernel<<<NN / 256, 256, 0, stream>>>(
      t, pos, poi_t, poi_pos, batch, (const float2*)udc, Wf, Bf, out);
}

// Round 7
// 72.575 us; speedup vs baseline: 1.4918x; 1.0241x over previous
//
#include <hip/hip_runtime.h>

#define NN 4194304
#define NB 16384

typedef _Float16 half4 __attribute__((ext_vector_type(4)));
typedef float floatx4 __attribute__((ext_vector_type(4)));
typedef unsigned int uint;

__device__ __forceinline__ uint pk_u32(float lo, float hi) {
  return __builtin_bit_cast(uint, __builtin_amdgcn_cvt_pkrtz(lo, hi));
}

// D-fragment (4 f32) -> B-fragment (4 f16) with ReLU, all in-register.
// Valid because D: col=lane&15,row=(lane>>4)*4+r  ==  B: col=lane&15,k=(lane>>4)*4+i.
__device__ __forceinline__ half4 relu_cvt(floatx4 d) {
  uint2 u;
  u.x = pk_u32(d[0], d[1]);
  u.y = pk_u32(d[2], d[3]);
  half4 h = __builtin_bit_cast(half4, u);
  return __builtin_elementwise_max(h, half4{0, 0, 0, 0});
}

// DPP butterfly wave64 sum; total lands in lane 63. 6 VALU adds, no LDS.
template <int CTRL>
__device__ __forceinline__ float dpp_add(float x) {
  int y = __builtin_amdgcn_update_dpp(0, __builtin_bit_cast(int, x), CTRL,
                                      0xf, 0xf, true);
  return x + __builtin_bit_cast(float, y);
}
__device__ __forceinline__ float wave_sum(float x) {
  x = dpp_add<0x111>(x);  // row_shr:1
  x = dpp_add<0x112>(x);  // row_shr:2
  x = dpp_add<0x114>(x);  // row_shr:4
  x = dpp_add<0x118>(x);  // row_shr:8  -> lane15/31/47/63 hold row sums
  x = dpp_add<0x142>(x);  // row_bcast:15 -> lane31 = rows0+1, lane63 = rows2+3
  x = dpp_add<0x143>(x);  // row_bcast:31 -> lane63 = total
  return x;
}

// Segmented reduce + atomics. Fast path: wave entirely in one segment
// (avg run length = 256 -> ~99% of waves) uses DPP butterfly + 1 atomic pair.
__device__ __forceinline__ void seg_atomic_add2(int b, float vx, float vy,
                                                float* __restrict__ out) {
  const int lane = threadIdx.x & 63;
  int b0 = __builtin_amdgcn_readfirstlane(b);
  if (__ballot(b == b0) == ~0ull) {  // wave-uniform branch
    float sx = wave_sum(vx);
    float sy = wave_sum(vy);
    if (lane == 63) {
      atomicAdd(&out[2 * b0], sx);
      atomicAdd(&out[2 * b0 + 1], sy);
    }
    return;
  }
  // Slow path: segmented inclusive scan (batch sorted).
  int bprev = __shfl_up(b, 1);
  bool head = (lane == 0) || (b != bprev);
  unsigned long long hb = __ballot(head);
  unsigned long long mask_le = hb << (63 - lane);
  int run_start = lane - __clzll(mask_le);
  float sx = vx, sy = vy;
#pragma unroll
  for (int off = 1; off < 64; off <<= 1) {
    float ox = __shfl_up(sx, off);
    float oy = __shfl_up(sy, off);
    if (lane - off >= run_start) { sx += ox; sy += oy; }
  }
  int bnext = __shfl_down(b, 1);
  bool tail = (lane == 63) || (b != bnext);
  if (tail) {
    atomicAdd(&out[2 * b], sx);
    atomicAdd(&out[2 * b + 1], sy);
  }
}

__global__ __launch_bounds__(256) void centroid_kernel(
    const float2* __restrict__ pos, const int* __restrict__ batch,
    float* __restrict__ csum) {
  int i = blockIdx.x * 256 + threadIdx.x;
  float2 p = pos[i];
  int b = batch[i];
  seg_atomic_add2(b, p.x, p.y, csum);
}

__global__ __launch_bounds__(256) void graphvec_kernel(
    const float* __restrict__ csum, const float2* __restrict__ poi_pos,
    float* __restrict__ udc) {
  int i = blockIdx.x * 256 + threadIdx.x;
  float2 pp = poi_pos[i];
  float dcx = csum[2 * i] - pp.x;
  float dcy = csum[2 * i + 1] - pp.y;
  float inv = rsqrtf(dcx * dcx + dcy * dcy);
  udc[2 * i] = dcx * inv;
  udc[2 * i + 1] = dcy * inv;
}

// Prepack weights into A-fragments of mfma_f32_16x16x16f16 (W as A: M=out,K=in):
// A[row=lane&15][k=(lane>>4)*4 + i], i=0..3, stored as uint2 (4 packed f16).
// 7 tiles: 0:L1(10x3) 1:L2 rows0-15(16x10) 2:L2 rows16-19(4x10)
//          3:L3 k0-15(10x16of20) 4:L3 k16-19(10x4) 5:L4(5x10) 6:L5(1x5)
// Bias sets (6 x 16 f32): 0:B1 1:B2[0:16] 2:B2[16:20] 3:B3 4:B4 5:B5
__global__ void prepack_kernel(
    const float* __restrict__ W1, const float* __restrict__ W2,
    const float* __restrict__ W3, const float* __restrict__ W4,
    const float* __restrict__ W5, const float* __restrict__ B1,
    const float* __restrict__ B2, const float* __restrict__ B3,
    const float* __restrict__ B4, const float* __restrict__ B5,
    uint2* __restrict__ Wf, float* __restrict__ Bf) {
  int p = blockIdx.x * 256 + threadIdx.x;
  if (p < 448) {
    int tile = p >> 6, lane = p & 63, row = lane & 15, kb = (lane >> 4) * 4;
    const float* W;
    int outb = 0, outc, K, ld, koff = 0;
    switch (tile) {
      case 0: W = W1; outc = 10; K = 3;  ld = 3;  break;
      case 1: W = W2; outc = 16; K = 10; ld = 10; break;
      case 2: W = W2; outb = 16; outc = 4; K = 10; ld = 10; break;
      case 3: W = W3; outc = 10; K = 16; ld = 20; break;
      case 4: W = W3; outc = 10; K = 4;  ld = 20; koff = 16; break;
      case 5: W = W4; outc = 5;  K = 10; ld = 10; break;
      default: W = W5; outc = 1; K = 5;  ld = 5;  break;
    }
    float v[4];
#pragma unroll
    for (int i = 0; i < 4; ++i) {
      int k = kb + i;
      v[i] = (row < outc && k < K) ? W[(outb + row) * ld + koff + k] : 0.f;
    }
    Wf[p] = uint2{pk_u32(v[0], v[1]), pk_u32(v[2], v[3])};
  } else if (p < 448 + 96) {
    int q = p - 448, set = q >> 4, n = q & 15;
    float v = 0.f;
    switch (set) {
      case 0: if (n < 10) v = B1[n]; break;
      case 1: v = B2[n]; break;
      case 2: if (n < 4) v = B2[16 + n]; break;
      case 3: if (n < 10) v = B3[n]; break;
      case 4: if (n < 5) v = B4[n]; break;
      default: if (n < 1) v = B5[0]; break;
    }
    Bf[q] = v;
  }
}

__device__ __forceinline__ floatx4 mfma16(half4 a, half4 b, floatx4 c) {
  return __builtin_amdgcn_mfma_f32_16x16x16f16(a, b, c, 0, 0, 0);
}

__global__ __launch_bounds__(256) void main_kernel(
    const float* __restrict__ t, const float2* __restrict__ pos,
    const float* __restrict__ poi_t, const float2* __restrict__ poi_pos,
    const int* __restrict__ batch, const float2* __restrict__ udc,
    const uint2* __restrict__ Wf, const float* __restrict__ Bf,
    float* __restrict__ out) {
  // Wave-private LDS, no barriers (intra-wave producer/consumer only).
  __shared__ uint2 feat_s[4][64];   // 4 f16 feats per node
  __shared__ float wbuf_s[4][64];   // final MLP scalar per node
  const int tid = threadIdx.x;
  const int lane = tid & 63;
  const int wid = tid >> 6;
  uint2* feat = feat_s[wid];
  float* wbuf = wbuf_s[wid];
  const int col = lane & 15;
  const int koct = lane >> 4;

  // Weight A-fragments (7 tiles x 4 f16) + bias C-fragments (6 x 4 f32).
  half4 wa[7];
#pragma unroll
  for (int k = 0; k < 7; ++k)
    wa[k] = __builtin_bit_cast(half4, Wf[k * 64 + lane]);
  floatx4 cb[6];
#pragma unroll
  for (int s = 0; s < 6; ++s)
    cb[s] = *(const floatx4*)&Bf[s * 16 + koct * 4];

  // Per-node features (thread = node).
  int i = blockIdx.x * 256 + tid;
  int b = batch[i];
  float2 p = pos[i];
  float tv = t[i];
  float2 pp = poi_pos[b];
  float2 u = udc[b];
  float f0 = tv - poi_t[b];
  float dpx = p.x - pp.x, dpy = p.y - pp.y;
  float f1 = dpx * dpx + dpy * dpy;
  float inv_r = rsqrtf(f1);
  float f2 = (dpx * u.x + dpy * u.y) * inv_r;

  feat[lane] = uint2{pk_u32(f0, f1), pk_u32(f2, 0.f)};

  // 4 groups of 16 nodes; 7 MFMAs per group, transitions fully in-register.
#pragma unroll
  for (int g = 0; g < 4; ++g) {
    // B1: col=node, k=feat; only koct 0 holds real k (0..3), rest zero.
    uint2 fr = feat[g * 16 + col];
    if (koct != 0) { fr.x = 0u; fr.y = 0u; }
    half4 b1 = __builtin_bit_cast(half4, fr);

    floatx4 d1 = mfma16(wa[0], b1, cb[0]);               // L1: 3->10
    half4 a2 = relu_cvt(d1);
    floatx4 d2a = mfma16(wa[1], a2, cb[1]);              // L2: 10->20 (two M tiles)
    floatx4 d2b = mfma16(wa[2], a2, cb[2]);
    half4 a3a = relu_cvt(d2a);
    half4 a3b = relu_cvt(d2b);
    floatx4 d3 = mfma16(wa[3], a3a, cb[3]);              // L3: 20->10 (K chained)
    d3 = mfma16(wa[4], a3b, d3);
    half4 a4 = relu_cvt(d3);
    floatx4 d4 = mfma16(wa[5], a4, cb[4]);               // L4: 10->5
    half4 a5 = relu_cvt(d4);
    floatx4 d5 = mfma16(wa[6], a5, cb[5]);               // L5: 5->1 (no relu)

    // w for node g*16+col sits at row 0 -> koct==0, reg 0.
    if (lane < 16) wbuf[g * 16 + lane] = d5[0];
  }

  float w = wbuf[lane];
  // F.normalize: unit = diff_pos * rsqrt(r2); reuse inv_r (guard f1==0 -> 0).
  float invn = (f1 > 0.f) ? inv_r : 0.f;
  seg_atomic_add2(b, w * dpx * invn, w * dpy * invn, out);
}

extern "C" void kernel_launch(void* const* d_in, const int* in_sizes, int n_in,
                              void* d_out, int out_size, void* d_ws,
                              size_t ws_size, hipStream_t stream) {
  const float* t = (const float*)d_in[0];
  const float2* pos = (const float2*)d_in[1];
  const float* poi_t = (const float*)d_in[2];
  const float2* poi_pos = (const float2*)d_in[3];
  const int* batch = (const int*)d_in[4];
  const float* W1 = (const float*)d_in[5];
  const float* B1 = (const float*)d_in[6];
  const float* W2 = (const float*)d_in[7];
  const float* B2 = (const float*)d_in[8];
  const float* W3 = (const float*)d_in[9];
  const float* B3 = (const float*)d_in[10];
  const float* W4 = (const float*)d_in[11];
  const float* B4 = (const float*)d_in[12];
  const float* W5 = (const float*)d_in[13];
  const float* B5 = (const float*)d_in[14];
  float* out = (float*)d_out;

  float* csum = (float*)d_ws;                  // [NB*2]
  float* udc = csum + 2 * NB;                  // [NB*2]
  uint2* Wf = (uint2*)(udc + 2 * NB);          // [448]
  float* Bf = (float*)(Wf + 448);              // [96]

  hipMemsetAsync(csum, 0, 2 * NB * sizeof(float), stream);
  hipMemsetAsync(d_out, 0, 2 * NB * sizeof(float), stream);

  prepack_kernel<<<3, 256, 0, stream>>>(W1, W2, W3, W4, W5, B1, B2, B3, B4,
                                        B5, Wf, Bf);
  centroid_kernel<<<NN / 256, 256, 0, stream>>>(pos, batch, csum);
  graphvec_kernel<<<NB / 256, 256, 0, stream>>>(csum, poi_pos, udc);
  main_kernel<<<NN / 256, 256, 0, stream>>>(
      t, pos, poi_t, poi_pos, batch, (const float2*)udc, Wf, Bf, out);
}

// Round 8
// 69.318 us; speedup vs baseline: 1.5619x; 1.0470x over previous
//
#include <hip/hip_runtime.h>

#define NN 4194304
#define NB 16384

typedef _Float16 half4 __attribute__((ext_vector_type(4)));
typedef float floatx4 __attribute__((ext_vector_type(4)));
typedef unsigned int uint;

__device__ __forceinline__ uint pk_u32(float lo, float hi) {
  return __builtin_bit_cast(uint, __builtin_amdgcn_cvt_pkrtz(lo, hi));
}

// D-fragment (4 f32) -> B-fragment (4 f16) with ReLU, all in-register.
// Valid because D: col=lane&15,row=(lane>>4)*4+r  ==  B: col=lane&15,k=(lane>>4)*4+i.
__device__ __forceinline__ half4 relu_cvt(floatx4 d) {
  uint2 u;
  u.x = pk_u32(d[0], d[1]);
  u.y = pk_u32(d[2], d[3]);
  half4 h = __builtin_bit_cast(half4, u);
  return __builtin_elementwise_max(h, half4{0, 0, 0, 0});
}

// DPP butterfly wave64 sum; total lands in lane 63. 6 VALU adds, no LDS.
template <int CTRL>
__device__ __forceinline__ float dpp_add(float x) {
  int y = __builtin_amdgcn_update_dpp(0, __builtin_bit_cast(int, x), CTRL,
                                      0xf, 0xf, true);
  return x + __builtin_bit_cast(float, y);
}
__device__ __forceinline__ float wave_sum(float x) {
  x = dpp_add<0x111>(x);  // row_shr:1
  x = dpp_add<0x112>(x);  // row_shr:2
  x = dpp_add<0x114>(x);  // row_shr:4
  x = dpp_add<0x118>(x);  // row_shr:8  -> lane15/31/47/63 hold row sums
  x = dpp_add<0x142>(x);  // row_bcast:15 -> lane31 = rows0+1, lane63 = rows2+3
  x = dpp_add<0x143>(x);  // row_bcast:31 -> lane63 = total
  return x;
}

// Segmented reduce + atomics. Fast path: wave entirely in one segment
// (avg run length = 256 -> ~99% of waves) uses DPP butterfly + 1 atomic pair.
__device__ __forceinline__ void seg_atomic_add2(int b, float vx, float vy,
                                                float* __restrict__ out) {
  const int lane = threadIdx.x & 63;
  int b0 = __builtin_amdgcn_readfirstlane(b);
  if (__ballot(b == b0) == ~0ull) {  // wave-uniform branch
    float sx = wave_sum(vx);
    float sy = wave_sum(vy);
    if (lane == 63) {
      atomicAdd(&out[2 * b0], sx);
      atomicAdd(&out[2 * b0 + 1], sy);
    }
    return;
  }
  // Slow path: segmented inclusive scan (batch sorted).
  int bprev = __shfl_up(b, 1);
  bool head = (lane == 0) || (b != bprev);
  unsigned long long hb = __ballot(head);
  unsigned long long mask_le = hb << (63 - lane);
  int run_start = lane - __clzll(mask_le);
  float sx = vx, sy = vy;
#pragma unroll
  for (int off = 1; off < 64; off <<= 1) {
    float ox = __shfl_up(sx, off);
    float oy = __shfl_up(sy, off);
    if (lane - off >= run_start) { sx += ox; sy += oy; }
  }
  int bnext = __shfl_down(b, 1);
  bool tail = (lane == 63) || (b != bnext);
  if (tail) {
    atomicAdd(&out[2 * b], sx);
    atomicAdd(&out[2 * b + 1], sy);
  }
}

__global__ __launch_bounds__(256) void centroid_kernel(
    const float2* __restrict__ pos, const int* __restrict__ batch,
    float* __restrict__ csum) {
  int i = blockIdx.x * 256 + threadIdx.x;
  float2 p = pos[i];
  int b = batch[i];
  seg_atomic_add2(b, p.x, p.y, csum);
}

__global__ __launch_bounds__(256) void graphvec_kernel(
    const float* __restrict__ csum, const float2* __restrict__ poi_pos,
    float* __restrict__ udc) {
  int i = blockIdx.x * 256 + threadIdx.x;
  float2 pp = poi_pos[i];
  float dcx = csum[2 * i] - pp.x;
  float dcy = csum[2 * i + 1] - pp.y;
  float inv = rsqrtf(dcx * dcx + dcy * dcy);
  udc[2 * i] = dcx * inv;
  udc[2 * i + 1] = dcy * inv;
}

// Prepack weights into A-fragments of mfma_f32_16x16x16f16 (W as A: M=out,K=in):
// A[row=lane&15][k=(lane>>4)*4 + i], stored as uint2 (4 packed f16).
// 7 tiles: 0:L1(10x3, bias folded at k=3) 1:L2 rows0-15(16x10) 2:L2 rows16-19
//          3:L3 k0-15(10x16of20) 4:L3 k16-19(10x4) 5:L4(5x10) 6:L5(1x5)
// Bias sets (5 x 16 f32): 0:B2[0:16] 1:B2[16:20] 2:B3 3:B4 4:B5
__global__ void prepack_kernel(
    const float* __restrict__ W1, const float* __restrict__ W2,
    const float* __restrict__ W3, const float* __restrict__ W4,
    const float* __restrict__ W5, const float* __restrict__ B1,
    const float* __restrict__ B2, const float* __restrict__ B3,
    const float* __restrict__ B4, const float* __restrict__ B5,
    uint2* __restrict__ Wf, float* __restrict__ Bf) {
  int p = blockIdx.x * 256 + threadIdx.x;
  if (p < 448) {
    int tile = p >> 6, lane = p & 63, row = lane & 15, kb = (lane >> 4) * 4;
    const float* W;
    int outb = 0, outc, K, ld, koff = 0;
    switch (tile) {
      case 0: W = W1; outc = 10; K = 3;  ld = 3;  break;
      case 1: W = W2; outc = 16; K = 10; ld = 10; break;
      case 2: W = W2; outb = 16; outc = 4; K = 10; ld = 10; break;
      case 3: W = W3; outc = 10; K = 16; ld = 20; break;
      case 4: W = W3; outc = 10; K = 4;  ld = 20; koff = 16; break;
      case 5: W = W4; outc = 5;  K = 10; ld = 10; break;
      default: W = W5; outc = 1; K = 5;  ld = 5;  break;
    }
    float v[4];
#pragma unroll
    for (int i = 0; i < 4; ++i) {
      int k = kb + i;
      v[i] = (row < outc && k < K) ? W[(outb + row) * ld + koff + k] : 0.f;
      if (tile == 0 && row < outc && k == 3) v[i] = B1[row];  // bias fold
    }
    Wf[p] = uint2{pk_u32(v[0], v[1]), pk_u32(v[2], v[3])};
  } else if (p < 448 + 80) {
    int q = p - 448, set = q >> 4, n = q & 15;
    float v = 0.f;
    switch (set) {
      case 0: v = B2[n]; break;
      case 1: if (n < 4) v = B2[16 + n]; break;
      case 2: if (n < 10) v = B3[n]; break;
      case 3: if (n < 5) v = B4[n]; break;
      default: if (n < 1) v = B5[0]; break;
    }
    Bf[q] = v;
  }
}

__device__ __forceinline__ floatx4 mfma16(half4 a, half4 b, floatx4 c) {
  return __builtin_amdgcn_mfma_f32_16x16x16f16(a, b, c, 0, 0, 0);
}

__global__ __launch_bounds__(256, 4) void main_kernel(
    const float* __restrict__ t, const float2* __restrict__ pos,
    const float* __restrict__ poi_t, const float2* __restrict__ poi_pos,
    const int* __restrict__ batch, const float2* __restrict__ udc,
    const uint2* __restrict__ Wf, const float* __restrict__ Bf,
    float* __restrict__ out) {
  // Wave-private LDS, no barriers (intra-wave producer/consumer only).
  __shared__ uint2 feat_s[4][64];   // 4 f16 feats per node
  __shared__ float wbuf_s[4][64];   // final MLP scalar per node
  const int tid = threadIdx.x;
  const int lane = tid & 63;
  const int wid = tid >> 6;
  uint2* feat = feat_s[wid];
  float* wbuf = wbuf_s[wid];
  const int col = lane & 15;
  const int koct = lane >> 4;

  // Weight A-fragments (7 tiles x 4 f16) + bias C-fragments (5 x 4 f32).
  half4 wa[7];
#pragma unroll
  for (int k = 0; k < 7; ++k)
    wa[k] = __builtin_bit_cast(half4, Wf[k * 64 + lane]);
  floatx4 cb[5];
#pragma unroll
  for (int s = 0; s < 5; ++s)
    cb[s] = *(const floatx4*)&Bf[s * 16 + koct * 4];
  floatx4 cz{0.f, 0.f, 0.f, 0.f};

  // Per-node features (thread = node).
  int i = blockIdx.x * 256 + tid;
  int b = batch[i];
  float2 p = pos[i];
  float tv = t[i];
  float2 pp = poi_pos[b];
  float2 u = udc[b];
  float f0 = tv - poi_t[b];
  float dpx = p.x - pp.x, dpy = p.y - pp.y;
  float f1 = dpx * dpx + dpy * dpy;
  float inv_r = rsqrtf(f1);
  float f2 = (dpx * u.x + dpy * u.y) * inv_r;

  // feat = {f0, f1, f2, 1.0}: the 1.0 multiplies the folded L1 bias column.
  feat[lane] = uint2{pk_u32(f0, f1), pk_u32(f2, 1.0f)};

  // 4 groups of 16 nodes; 7 MFMAs per group, transitions fully in-register.
#pragma unroll
  for (int g = 0; g < 4; ++g) {
    // B1: col=node, k=feat. koct>0 lanes carry finite junk; W1 A-frag is
    // zero for k>=4 so the products vanish exactly - no masking needed.
    half4 b1 = __builtin_bit_cast(half4, feat[g * 16 + col]);

    floatx4 d1 = mfma16(wa[0], b1, cz);                  // L1: 3->10 (+bias)
    half4 a2 = relu_cvt(d1);
    floatx4 d2a = mfma16(wa[1], a2, cb[0]);              // L2: 10->20 (two M tiles)
    floatx4 d2b = mfma16(wa[2], a2, cb[1]);
    half4 a3a = relu_cvt(d2a);
    half4 a3b = relu_cvt(d2b);
    floatx4 d3 = mfma16(wa[3], a3a, cb[2]);              // L3: 20->10 (K chained)
    d3 = mfma16(wa[4], a3b, d3);
    half4 a4 = relu_cvt(d3);
    floatx4 d4 = mfma16(wa[5], a4, cb[3]);               // L4: 10->5
    half4 a5 = relu_cvt(d4);
    floatx4 d5 = mfma16(wa[6], a5, cb[4]);               // L5: 5->1 (no relu)

    // w for node g*16+col sits at row 0 -> koct==0, reg 0.
    if (lane < 16) wbuf[g * 16 + lane] = d5[0];
  }

  float w = wbuf[lane];
  // F.normalize: unit = diff_pos * rsqrt(r2); reuse inv_r (guard f1==0 -> 0).
  float invn = (f1 > 0.f) ? inv_r : 0.f;
  seg_atomic_add2(b, w * dpx * invn, w * dpy * invn, out);
}

extern "C" void kernel_launch(void* const* d_in, const int* in_sizes, int n_in,
                              void* d_out, int out_size, void* d_ws,
                              size_t ws_size, hipStream_t stream) {
  const float* t = (const float*)d_in[0];
  const float2* pos = (const float2*)d_in[1];
  const float* poi_t = (const float*)d_in[2];
  const float2* poi_pos = (const float2*)d_in[3];
  const int* batch = (const int*)d_in[4];
  const float* W1 = (const float*)d_in[5];
  const float* B1 = (const float*)d_in[6];
  const float* W2 = (const float*)d_in[7];
  const float* B2 = (const float*)d_in[8];
  const float* W3 = (const float*)d_in[9];
  const float* B3 = (const float*)d_in[10];
  const float* W4 = (const float*)d_in[11];
  const float* B4 = (const float*)d_in[12];
  const float* W5 = (const float*)d_in[13];
  const float* B5 = (const float*)d_in[14];
  float* out = (float*)d_out;

  float* csum = (float*)d_ws;                  // [NB*2]
  float* udc = csum + 2 * NB;                  // [NB*2]
  uint2* Wf = (uint2*)(udc + 2 * NB);          // [448]
  float* Bf = (float*)(Wf + 448);              // [80]

  hipMemsetAsync(csum, 0, 2 * NB * sizeof(float), stream);
  hipMemsetAsync(d_out, 0, 2 * NB * sizeof(float), stream);

  prepack_kernel<<<3, 256, 0, stream>>>(W1, W2, W3, W4, W5, B1, B2, B3, B4,
                                        B5, Wf, Bf);
  centroid_kernel<<<NN / 256, 256, 0, stream>>>(pos, batch, csum);
  graphvec_kernel<<<NB / 256, 256, 0, stream>>>(csum, poi_pos, udc);
  main_kernel<<<NN / 256, 256, 0, stream>>>(
      t, pos, poi_t, poi_pos, batch, (const float2*)udc, Wf, Bf, out);
}